// Round 4
// baseline (60.341 us; speedup 1.0000x reference)
//
#include <hip/hip_runtime.h>
#include <hip/hip_bf16.h>

#define IN 8192
#define OUT 8192

typedef __bf16 bf16x8 __attribute__((ext_vector_type(8)));
typedef float f32x4 __attribute__((ext_vector_type(4)));
typedef unsigned short u16;
typedef unsigned int u32;
typedef u32 u32x4 __attribute__((ext_vector_type(4)));

#define MFMA(a, b, c) __builtin_amdgcn_mfma_f32_16x16x32_bf16(a, b, c, 0, 0, 0)

static __device__ __forceinline__ u16 f2bf(float v) {
    __hip_bfloat16 h = __float2bfloat16(v);
    return __builtin_bit_cast(u16, h);
}
static __device__ __forceinline__ float bf2f(u16 h) {
    union { u32 u; float f; } cv; cv.u = ((u32)h) << 16; return cv.f;
}
static __device__ __forceinline__ void split_hl(float v, u16& hi, u16& lo) {
    hi = f2bf(v);
    lo = f2bf(v - bf2f(hi));
}
static __device__ __forceinline__ bf16x8 ld8(const u16* p) {
    return *reinterpret_cast<const bf16x8*>(p);
}

// ================= init: inverse permutations =================
__global__ __launch_bounds__(1024)
void init_kernel(const int* __restrict__ voutp, const int* __restrict__ uinp,
                 int* __restrict__ invv, int* __restrict__ invu) {
    int p = blockIdx.x * 1024 + threadIdx.x;
    invv[voutp[p]] = p;
    invu[uinp[p]] = p;
}

// ================= pre: block (b, lc) computes Z[:, 16lc:16lc+16], scatters to xt =================
// X[j][n] = x[b, vinp[j*128+n]]/shw[...]; T = v1 @ X (full, duplicated);
// Z_chunk = T @ v2[lc-rows]^T; xt[b, invv[i*128+l]] = bf16(Z[i][l]); Spart[b][lc] = sum bf16(Z).
__global__ __launch_bounds__(512)
void pre_kernel(const float* __restrict__ x, const float* __restrict__ shw,
                const int* __restrict__ vinp, const int* __restrict__ invv,
                const float* __restrict__ v1, const float* __restrict__ v2,
                u16* __restrict__ xt, float* __restrict__ Spart) {
    __shared__ alignas(16) u16 sV1[2][64 * 72];     // v1 hi/lo [i][j] stride 72
    __shared__ alignas(16) u16 sX[2][128 * 72];     // X^T [n][j] stride 72; reused as T [i][k] stride 136
    __shared__ alignas(16) u16 sV2c[2][16 * 136];   // v2 chunk rows [r][k] stride 136
    __shared__ float sred[8];
    const int tid = threadIdx.x;
    const int b = blockIdx.x >> 3, lc = blockIdx.x & 7;
    const int lane = tid & 63, w = tid >> 6;
    const int l15 = lane & 15, l4 = lane >> 4;

    #pragma unroll
    for (int it = 0; it < 8; ++it) {                // v1: 4096
        int e = tid + it * 512;
        u16 h, l; split_hl(v1[e], h, l);
        int idx = (e >> 6) * 72 + (e & 63);
        sV1[0][idx] = h; sV1[1][idx] = l;
    }
    #pragma unroll
    for (int it = 0; it < 4; ++it) {                // v2 chunk: 16 rows x 128
        int e = tid + it * 512;                     // e = r*128 + k
        u16 h, l; split_hl(v2[(lc * 16 + (e >> 7)) * 128 + (e & 127)], h, l);
        int idx = (e >> 7) * 136 + (e & 127);
        sV2c[0][idx] = h; sV2c[1][idx] = l;
    }
    #pragma unroll
    for (int it = 0; it < 16; ++it) {               // X gather: 8192, store X^T [n][j]
        int e = tid + it * 512;                     // e = j*128 + n
        int gi = vinp[e];
        float v = x[b * IN + gi] / shw[gi];
        u16 h, l; split_hl(v, h, l);
        int idx = (e & 127) * 72 + (e >> 7);
        sX[0][idx] = h; sX[1][idx] = l;
    }
    __syncthreads();

    // stage1: T = v1 @ X (M=64,N=128,K=64). wave w -> n-tile w, m-tiles 0..3.
    f32x4 acc[4] = {{0,0,0,0},{0,0,0,0},{0,0,0,0},{0,0,0,0}};
    #pragma unroll
    for (int ks = 0; ks < 2; ++ks) {
        int bo = (w * 16 + l15) * 72 + ks * 32 + l4 * 8;
        bf16x8 bh = ld8(&sX[0][bo]), bl = ld8(&sX[1][bo]);
        #pragma unroll
        for (int mt = 0; mt < 4; ++mt) {
            int ao = (mt * 16 + l15) * 72 + ks * 32 + l4 * 8;
            bf16x8 ah = ld8(&sV1[0][ao]), al = ld8(&sV1[1][ao]);
            acc[mt] = MFMA(ah, bh, acc[mt]);
            acc[mt] = MFMA(ah, bl, acc[mt]);
            acc[mt] = MFMA(al, bh, acc[mt]);
        }
    }
    __syncthreads();                                // all waves done reading sX
    u16* Thi = sX[0]; u16* Tlo = sX[1];             // T [i][k] stride 136
    #pragma unroll
    for (int mt = 0; mt < 4; ++mt) {
        #pragma unroll
        for (int r = 0; r < 4; ++r) {
            int i = mt * 16 + l4 * 4 + r;
            u16 h, l; split_hl(acc[mt][r], h, l);
            Thi[i * 136 + w * 16 + l15] = h;
            Tlo[i * 136 + w * 16 + l15] = l;
        }
    }
    __syncthreads();

    // stage2: Z chunk = T @ v2c^T (M=64,N=16,K=128). waves 0..3: m-tile = w.
    float ssum = 0.f;
    if (w < 4) {
        f32x4 z = {0.f, 0.f, 0.f, 0.f};
        #pragma unroll
        for (int ks = 0; ks < 4; ++ks) {
            int bo = l15 * 136 + ks * 32 + l4 * 8;
            bf16x8 bh = ld8(&sV2c[0][bo]), bl = ld8(&sV2c[1][bo]);
            int ao = (w * 16 + l15) * 136 + ks * 32 + l4 * 8;
            bf16x8 ah = ld8(&Thi[ao]), al = ld8(&Tlo[ao]);
            z = MFMA(ah, bh, z); z = MFMA(ah, bl, z); z = MFMA(al, bh, z);
        }
        #pragma unroll
        for (int r = 0; r < 4; ++r) {
            int i = w * 16 + l4 * 4 + r;
            int q = i * 128 + lc * 16 + l15;
            u16 zb = f2bf(z[r]);
            xt[(size_t)b * IN + invv[q]] = zb;
            ssum += bf2f(zb);
        }
    }
    #pragma unroll
    for (int off = 32; off; off >>= 1) ssum += __shfl_down(ssum, off, 64);
    if (lane == 0) sred[w] = ssum;
    __syncthreads();
    if (tid == 0) {
        float t = 0.f;
        #pragma unroll
        for (int i = 0; i < 8; ++i) t += sred[i];
        Spart[b * 8 + lc] = t;
    }
}

// ================= qgemm: G[pl][b][o] = sum_{k in plane pl} xt[b,k]*code(k,o) =================
__global__ __launch_bounds__(256)
void qgemm_kernel(const int* __restrict__ qw, const u16* __restrict__ xt,
                  float* __restrict__ G) {
    __shared__ alignas(16) u16 sA[16 * 2056];       // xt tile [16][2048] padded +8
    const int tid = threadIdx.x;
    const int lane = tid & 63, w = tid >> 6;
    const int l15 = lane & 15, l4 = lane >> 4;
    const int k0 = blockIdx.y * 2048;
    #pragma unroll
    for (int i = 0; i < 16; ++i) {
        int idx = tid + i * 256;
        int r = idx >> 8, c = idx & 255;
        *reinterpret_cast<u32x4*>(&sA[r * 2056 + c * 8]) =
            *reinterpret_cast<const u32x4*>(&xt[(size_t)r * IN + k0 + c * 8]);
    }
    __syncthreads();
    const int o = blockIdx.x * 64 + w * 16 + l15;
    const int* qp = qw + (size_t)(k0 / 8 + l4) * OUT + o;
    f32x4 acc = {0.f, 0.f, 0.f, 0.f};
    #pragma unroll 8
    for (int kt = 0; kt < 64; ++kt) {
        u32 q = (u32)qp[(size_t)kt * 4 * OUT];
        bf16x8 a = ld8(&sA[l15 * 2056 + kt * 32 + l4 * 8]);
        u32 ev = q & 0x0F0F0F0Fu, od = (q >> 4) & 0x0F0F0F0Fu;
        float f0, f1, f2, f3, f4, f5, f6, f7;
        asm("v_cvt_f32_ubyte0 %0, %1" : "=v"(f0) : "v"(ev));
        asm("v_cvt_f32_ubyte0 %0, %1" : "=v"(f1) : "v"(od));
        asm("v_cvt_f32_ubyte1 %0, %1" : "=v"(f2) : "v"(ev));
        asm("v_cvt_f32_ubyte1 %0, %1" : "=v"(f3) : "v"(od));
        asm("v_cvt_f32_ubyte2 %0, %1" : "=v"(f4) : "v"(ev));
        asm("v_cvt_f32_ubyte2 %0, %1" : "=v"(f5) : "v"(od));
        asm("v_cvt_f32_ubyte3 %0, %1" : "=v"(f6) : "v"(ev));
        asm("v_cvt_f32_ubyte3 %0, %1" : "=v"(f7) : "v"(od));
        u32 p0, p1, p2, p3;
        asm("v_cvt_pk_bf16_f32 %0, %1, %2" : "=v"(p0) : "v"(f0), "v"(f1));
        asm("v_cvt_pk_bf16_f32 %0, %1, %2" : "=v"(p1) : "v"(f2), "v"(f3));
        asm("v_cvt_pk_bf16_f32 %0, %1, %2" : "=v"(p2) : "v"(f4), "v"(f5));
        asm("v_cvt_pk_bf16_f32 %0, %1, %2" : "=v"(p3) : "v"(f6), "v"(f7));
        u32x4 pk = {p0, p1, p2, p3};
        acc = MFMA(a, __builtin_bit_cast(bf16x8, pk), acc);
    }
    float* g = G + ((size_t)blockIdx.y * 16 + l4 * 4) * OUT + o;
    #pragma unroll
    for (int r = 0; r < 4; ++r) g[(size_t)r * OUT] = acc[r];
}

// ================= post: block (b, lc) computes Zp[:, 16lc:16lc+16], scatters to out =================
// og[j][n] = scale[o]*((2/15)*Gs[o] - S[b]), o = uoutp[j*128+n]; t2 = u1^T @ og (full);
// Zp_chunk = t2 @ u2[:, lc-cols]; out[b, invu[i*128+l]] = Zp[i][l] + bias[invu[...]].
__global__ __launch_bounds__(512)
void post_kernel(const float* __restrict__ G, const float* __restrict__ Spart,
                 const int* __restrict__ uoutp, const int* __restrict__ invu,
                 const float* __restrict__ scale, const float* __restrict__ u1,
                 const float* __restrict__ u2, const float* __restrict__ bias,
                 float* __restrict__ out) {
    __shared__ alignas(16) u16 sU1[2][64 * 72];     // u1^T [i][j] stride 72
    __shared__ alignas(16) u16 sOG[2][128 * 72];    // og^T [n][j] stride 72; reused as t2 [i][k] stride 136
    __shared__ alignas(16) u16 sU2c[2][16 * 136];   // u2 col-chunk [r][k] stride 136
    const int tid = threadIdx.x;
    const int b = blockIdx.x >> 3, lc = blockIdx.x & 7;
    const int lane = tid & 63, w = tid >> 6;
    const int l15 = lane & 15, l4 = lane >> 4;

    float Sb = 0.f;
    #pragma unroll
    for (int c = 0; c < 8; ++c) Sb += Spart[b * 8 + c];

    #pragma unroll
    for (int it = 0; it < 8; ++it) {                // u1^T: u1[j*64+i] -> [i][j]
        int e = tid + it * 512;
        u16 h, l; split_hl(u1[e], h, l);
        int idx = (e & 63) * 72 + (e >> 6);
        sU1[0][idx] = h; sU1[1][idx] = l;
    }
    #pragma unroll
    for (int it = 0; it < 4; ++it) {                // u2 col-chunk: u2[k][16lc+r] -> [r][k]
        int e = tid + it * 512;                     // e = k*16 + r
        int r = e & 15, k = e >> 4;
        u16 h, l; split_hl(u2[k * 128 + lc * 16 + r], h, l);
        sU2c[0][r * 136 + k] = h; sU2c[1][r * 136 + k] = l;
    }
    #pragma unroll
    for (int it = 0; it < 16; ++it) {               // og gather: 8192, store og^T [n][j]
        int e = tid + it * 512;                     // e = j*128 + n
        int o = uoutp[e];
        float gs = G[(size_t)b * OUT + o] + G[(size_t)(16 + b) * OUT + o]
                 + G[(size_t)(32 + b) * OUT + o] + G[(size_t)(48 + b) * OUT + o];
        float v = scale[o] * (gs * (2.0f / 15.0f) - Sb);
        u16 h, l; split_hl(v, h, l);
        int idx = (e & 127) * 72 + (e >> 7);
        sOG[0][idx] = h; sOG[1][idx] = l;
    }
    __syncthreads();

    // stage1: t2 = u1^T @ og (M=64,N=128,K=64). wave w -> n-tile w, m-tiles 0..3.
    f32x4 acc[4] = {{0,0,0,0},{0,0,0,0},{0,0,0,0},{0,0,0,0}};
    #pragma unroll
    for (int ks = 0; ks < 2; ++ks) {
        int bo = (w * 16 + l15) * 72 + ks * 32 + l4 * 8;
        bf16x8 bh = ld8(&sOG[0][bo]), bl = ld8(&sOG[1][bo]);
        #pragma unroll
        for (int mt = 0; mt < 4; ++mt) {
            int ao = (mt * 16 + l15) * 72 + ks * 32 + l4 * 8;
            bf16x8 ah = ld8(&sU1[0][ao]), al = ld8(&sU1[1][ao]);
            acc[mt] = MFMA(ah, bh, acc[mt]);
            acc[mt] = MFMA(ah, bl, acc[mt]);
            acc[mt] = MFMA(al, bh, acc[mt]);
        }
    }
    __syncthreads();
    u16* Thi = sOG[0]; u16* Tlo = sOG[1];           // t2 [i][k] stride 136
    #pragma unroll
    for (int mt = 0; mt < 4; ++mt) {
        #pragma unroll
        for (int r = 0; r < 4; ++r) {
            int i = mt * 16 + l4 * 4 + r;
            u16 h, l; split_hl(acc[mt][r], h, l);
            Thi[i * 136 + w * 16 + l15] = h;
            Tlo[i * 136 + w * 16 + l15] = l;
        }
    }
    __syncthreads();

    // stage2: Zp chunk = t2 @ u2c (M=64,N=16,K=128). waves 0..3: m-tile = w.
    if (w < 4) {
        f32x4 z = {0.f, 0.f, 0.f, 0.f};
        #pragma unroll
        for (int ks = 0; ks < 4; ++ks) {
            int bo = l15 * 136 + ks * 32 + l4 * 8;
            bf16x8 bh = ld8(&sU2c[0][bo]), bl = ld8(&sU2c[1][bo]);
            int ao = (w * 16 + l15) * 136 + ks * 32 + l4 * 8;
            bf16x8 ah = ld8(&Thi[ao]), al = ld8(&Tlo[ao]);
            z = MFMA(ah, bh, z); z = MFMA(ah, bl, z); z = MFMA(al, bh, z);
        }
        #pragma unroll
        for (int r = 0; r < 4; ++r) {
            int i = w * 16 + l4 * 4 + r;
            int q = i * 128 + lc * 16 + l15;
            int p = invu[q];
            out[(size_t)b * OUT + p] = z[r] + bias[p];
        }
    }
}

extern "C" void kernel_launch(void* const* d_in, const int* in_sizes, int n_in,
                              void* d_out, int out_size, void* d_ws, size_t ws_size,
                              hipStream_t stream) {
    const float* x     = (const float*)d_in[0];
    const int*   qw    = (const int*)d_in[1];
    const float* scale = (const float*)d_in[2];
    const float* shw   = (const float*)d_in[3];
    const float* v1    = (const float*)d_in[4];
    const float* v2    = (const float*)d_in[5];
    const float* u1    = (const float*)d_in[6];
    const float* u2    = (const float*)d_in[7];
    const float* bias  = (const float*)d_in[8];
    const int* vinp  = (const int*)d_in[9];
    const int* voutp = (const int*)d_in[10];
    const int* uinp  = (const int*)d_in[11];
    const int* uoutp = (const int*)d_in[12];
    float* out = (float*)d_out;

    char* ws = (char*)d_ws;
    u16*   xt    = (u16*)ws;                        // 256 KiB  [16][8192] bf16
    float* G     = (float*)(ws + (256 << 10));      // 2 MiB    [4][16][8192] f32
    float* Spart = (float*)(ws + (2304 << 10));     // 512 B    [16][8] f32
    int*   invv  = (int*)(ws + (2305 << 10));       // 32 KiB
    int*   invu  = (int*)(ws + (2337 << 10));       // 32 KiB

    init_kernel<<<8, 1024, 0, stream>>>(voutp, uinp, invv, invu);
    pre_kernel<<<128, 512, 0, stream>>>(x, shw, vinp, invv, v1, v2, xt, Spart);
    qgemm_kernel<<<dim3(128, 4), 256, 0, stream>>>(qw, xt, G);
    post_kernel<<<128, 512, 0, stream>>>(G, Spart, uoutp, invu, scale, u1, u2, bias, out);
}